// Round 8
// baseline (27467.023 us; speedup 1.0000x reference)
//
#include <hip/hip_runtime.h>
#include <math.h>

// EarthMoverDistance: exact integer Jonker-Volgenant. B=8, N=1024, 3-D
// Euclidean cost quantized to u16 (scale 4096; matching-swap error bound
// 2.4e-4 vs 6.6e-3 threshold; final sum recomputed in fp32 from coords).
// One wave per batch; lane owns 16 columns (c = lane*16+k) in registers.
// R8 = R7 with the settled-column bug fixed: R7's BIGOFF trick let later
// expands overwrite way[] of settled columns (cur ~ 5.4e8 < INFI -> upd
// true), corrupting the augmenting path -> absmax 1.95e-2. Reverted to the
// R1-R3-validated used-bitmask gate in expand; BIGOFF removed everywhere.
// Pipeline: u16 cost cache (2 MB/batch, L2-resident) -> integer column
// reduction -> greedy -> reduction transfer -> 2-pass integer auction
// (terminates: every strict step decreases a dual by >=1 quantum; guarded,
// falls through to exact SSP) -> exact SSP with deferred dual updates.

#define N      1024
#define BATCH  8
#define NSLOT  16
#define INFI   0x3FFFFFFF
#define SCANMAX 8192
#define QCAP   9300
#define SCALE  4096.0f

__global__ void emd_zero_kernel(float* out) { out[0] = 0.0f; }

// ---- cost cache: Dq[b][r][c] = round(dist * 4096), clamped u16 ----
__global__ __launch_bounds__(256)
void emd_dist_kernel(const float* __restrict__ S1, const float* __restrict__ S2,
                     unsigned short* __restrict__ D) {
    int b = blockIdx.x >> 10;
    int r = blockIdx.x & (N - 1);
    const float* s1 = S1 + ((size_t)b * N + r) * 3;
    float x1 = s1[0], y1 = s1[1], z1 = s1[2];
    const float* s2 = S2 + (size_t)b * N * 3;
    unsigned short* drow = D + ((size_t)b * N + r) * (size_t)N;
    for (int c = threadIdx.x; c < N; c += 256) {
        float dx = x1 - s2[3 * c], dy = y1 - s2[3 * c + 1], dz = z1 - s2[3 * c + 2];
        float d = sqrtf(dx * dx + dy * dy + dz * dz);
        int qv = (int)(d * SCALE + 0.5f);
        drow[c] = (unsigned short)(qv > 65535 ? 65535 : qv);
    }
}

// ---- column reduction: V[c] = min_r Dq[r][c] (int), I = argmin row ----
__global__ __launch_bounds__(256)
void emd_colmin_kernel(const unsigned short* __restrict__ D,
                       int* __restrict__ V, int* __restrict__ I) {
    int b = blockIdx.x >> 2;
    int c = ((blockIdx.x & 3) << 8) + threadIdx.x;
    const unsigned short* Db = D + ((size_t)b << 20);
    int best = INFI, bi = 1;
    for (int r = 0; r < N; ++r) {
        int d = Db[(size_t)r * N + c];
        if (d < best) { best = d; bi = r + 1; }
    }
    V[b * N + c] = best;
    I[b * N + c] = bi;
}

__device__ __forceinline__ unsigned umin32(unsigned a, unsigned b) { return a < b ? a : b; }

template<int CTRL>
__device__ __forceinline__ unsigned dppmin_u32(unsigned x) {
    int y = __builtin_amdgcn_update_dpp((int)x, (int)x, CTRL, 0xF, 0xF, false);
    return umin32(x, (unsigned)y);
}
__device__ __forceinline__ unsigned wave_min_u32(unsigned x) {
    x = dppmin_u32<0x111>(x);   // row_shr:1
    x = dppmin_u32<0x112>(x);   // row_shr:2
    x = dppmin_u32<0x114>(x);   // row_shr:4
    x = dppmin_u32<0x118>(x);   // row_shr:8
    x = dppmin_u32<0x142>(x);   // row_bcast:15
    x = dppmin_u32<0x143>(x);   // row_bcast:31
    return (unsigned)__builtin_amdgcn_readlane((int)x, 63);
}

template<bool CACHED>
__global__ __launch_bounds__(64, 1)
void emd_jv_kernel(const float* __restrict__ S1,
                   const float* __restrict__ S2,
                   const unsigned short* __restrict__ Dc,
                   const int* __restrict__ Vin,
                   const int* __restrict__ Iin,
                   float* __restrict__ out) {
    __shared__ float4 s1c[N + 1];     // row coords (final fp32 sum; !CACHED costs)
    __shared__ int    u_lds[N + 1];   // row potentials (int)
    __shared__ int    den[N + 1];     // D value when column settled
    __shared__ int    rowm[N + 1];    // row -> matched col (0 = free)
    __shared__ int    q[QCAP];        // auction work queue
    __shared__ int    qcnt;

    const int lane = threadIdx.x;
    const int b = blockIdx.x;
    const float* s1g = S1 + (size_t)b * N * 3;
    const float* s2g = S2 + (size_t)b * N * 3;
    const unsigned short* Db = CACHED ? (Dc + ((size_t)b << 20)) : (const unsigned short*)0;

    for (int t = lane; t < N; t += 64) {
        s1c[t + 1] = make_float4(s1g[3 * t], s1g[3 * t + 1], s1g[3 * t + 2], 0.0f);
        u_lds[t + 1] = 0; rowm[t + 1] = 0;
    }
    if (lane == 0) { u_lds[0] = 0; rowm[0] = 0; qcnt = 0; }

    // per-lane column state: col j = c+1, c = lane*16+k
    int nv[NSLOT];    // NEGATED column dual (-v)
    int jpk[NSLOT];   // (matched_row<<11)|j ; row 0 = free
    int im[NSLOT];
    float x2[NSLOT], y2[NSLOT], z2[NSLOT];   // !CACHED cost compute only

    if (!CACHED) {
#pragma unroll
        for (int k = 0; k < NSLOT; ++k) {
            int pt = lane * NSLOT + k;
            x2[k] = s2g[3 * pt]; y2[k] = s2g[3 * pt + 1]; z2[k] = s2g[3 * pt + 2];
        }
    }
    __syncthreads();

    if (CACHED) {
#pragma unroll
        for (int k = 0; k < NSLOT; ++k) {
            int c = lane * NSLOT + k;
            nv[k] = -Vin[b * N + c];
            im[k] = Iin[b * N + c];
        }
    } else {
        int bd[NSLOT];
#pragma unroll
        for (int k = 0; k < NSLOT; ++k) { bd[k] = INFI; im[k] = 1; }
        for (int r = 1; r <= N; ++r) {
            float4 qq = s1c[r];
#pragma unroll
            for (int k = 0; k < NSLOT; ++k) {
                float dx = qq.x - x2[k], dy = qq.y - y2[k], dz = qq.z - z2[k];
                float dd = sqrtf(dx * dx + dy * dy + dz * dz);
                int di = (int)(dd * SCALE + 0.5f); if (di > 65535) di = 65535;
                if (di < bd[k]) { bd[k] = di; im[k] = r; }
            }
        }
#pragma unroll
        for (int k = 0; k < NSLOT; ++k) nv[k] = -bd[k];
    }

    // ---- greedy matching on tight edges ----
#pragma unroll
    for (int k = 0; k < NSLOT; ++k) {
        int j = lane * NSLOT + k + 1;
        int r = im[k];
        int old = atomicCAS(&rowm[r], 0, j);
        jpk[k] = ((old == 0 ? r : 0) << 11) | j;
    }
    __syncthreads();

    // ---- helpers ----
    auto loadrow = [&](int rr, int* d) {
        if (CACHED) {
            const uint4* p = (const uint4*)(Db + (size_t)(rr - 1) * N);
            uint4 w0 = p[lane * 2], w1 = p[lane * 2 + 1];
            unsigned ww[8] = {w0.x, w0.y, w0.z, w0.w, w1.x, w1.y, w1.z, w1.w};
#pragma unroll
            for (int t = 0; t < 8; ++t) {
                d[2 * t] = (int)(ww[t] & 0xFFFFu);
                d[2 * t + 1] = (int)(ww[t] >> 16);
            }
        } else {
            float4 qq = s1c[rr];
#pragma unroll
            for (int k = 0; k < NSLOT; ++k) {
                float dx = qq.x - x2[k], dy = qq.y - y2[k], dz = qq.z - z2[k];
                float dd = sqrtf(dx * dx + dy * dy + dz * dz);
                int di = (int)(dd * SCALE + 0.5f); if (di > 65535) di = 65535;
                d[k] = di;
            }
        }
    };

    auto treemin = [&](const unsigned* keys) -> unsigned {
        unsigned t[8];
#pragma unroll
        for (int i0 = 0; i0 < 8; ++i0) t[i0] = umin32(keys[2 * i0], keys[2 * i0 + 1]);
#pragma unroll
        for (int i0 = 0; i0 < 4; ++i0) t[i0] = umin32(t[2 * i0], t[2 * i0 + 1]);
        t[0] = umin32(t[0], t[1]);
        t[1] = umin32(t[2], t[3]);
        return umin32(t[0], t[1]);
    };

    // min1/min2 of (cost(rr,.) - v) as packed keys (slack<<11)|col; exact:
    // clamp at 0x1FFFFF never binds on min1/min2 (duals stay O(2^17)).
    auto scan2 = [&](int rr, unsigned& k1, unsigned& k2) {
        int d[NSLOT]; loadrow(rr, d);
        unsigned keys[NSLOT];
#pragma unroll
        for (int k = 0; k < NSLOT; ++k) {
            unsigned cu = umin32((unsigned)(d[k] + nv[k]), 0x1FFFFFu);
            keys[k] = (cu << 11) | (unsigned)(lane * NSLOT + k + 1);
        }
        k1 = wave_min_u32(treemin(keys));
        int j1 = (int)(k1 & 0x7FF);
        int lo = (j1 - 1) >> 4, kk = (j1 - 1) & 15;
        if (lane == lo) {
#pragma unroll
            for (int k = 0; k < NSLOT; ++k) if (k == kk) keys[k] = 0xFFFFFFFFu;
        }
        k2 = wave_min_u32(treemin(keys));
    };

    auto colrow = [&](int j) -> int {     // matched row of col j (uniform)
        int lo = (j - 1) >> 4, kk = (j - 1) & 15;
        int sel = jpk[0];
#pragma unroll
        for (int k = 1; k < NSLOT; ++k) if (k == kk) sel = jpk[k];
        return __builtin_amdgcn_readlane(sel, lo) >> 11;
    };

    // ---- reduction transfer (matched rows; sequential like lapjv) ----
    for (int i = 1; i <= N; ++i) {
        int j1 = __builtin_amdgcn_readfirstlane(rowm[i]);
        if (j1 == 0) continue;
        unsigned k1, k2; scan2(i, k1, k2);
        int mu = (int)((((int)(k1 & 0x7FF) == j1) ? k2 : k1) >> 11);
        int lo = (j1 - 1) >> 4, kk = (j1 - 1) & 15;
        if (lane == lo) {
#pragma unroll
            for (int k = 0; k < NSLOT; ++k) if (k == kk) nv[k] += mu;  // v -= mu
        }
        if (lane == 0) u_lds[i] = mu;
    }

    // ---- augmenting row reduction (integer auction, 2 passes) ----
    for (int t = lane + 1; t <= N; t += 64)
        if (rowm[t] == 0) { int x = atomicAdd(&qcnt, 1); q[x] = t; }
    __syncthreads();
    {
        int e = __builtin_amdgcn_readfirstlane(qcnt);
        int s = 0, ne = e, scans = 0;
        bool bail = false;
        for (int pass = 0; pass < 2 && !bail; ++pass) {
            int k = s;
            while (k < e && !bail) {
                __syncthreads();
                int i = __builtin_amdgcn_readfirstlane(q[k]); ++k;
                for (;;) {
                    if (++scans > SCANMAX) { bail = true; break; }
                    unsigned k1, k2; scan2(i, k1, k2);
                    int m1 = (int)(k1 >> 11), m2 = (int)(k2 >> 11);
                    int j1 = (int)(k1 & 0x7FF);
                    bool dec = m1 < m2;
                    int i0 = colrow(j1);
                    if (!dec && i0 != 0) { j1 = (int)(k2 & 0x7FF); i0 = colrow(j1); }
                    int lo = (j1 - 1) >> 4, kk = (j1 - 1) & 15;
                    if (lane == lo) {
#pragma unroll
                        for (int kq = 0; kq < NSLOT; ++kq) if (kq == kk) {
                            if (dec) nv[kq] += (m2 - m1);   // v[j1] -= (m2-m1)
                            jpk[kq] = (i << 11) | j1;
                        }
                    }
                    if (lane == 0) {
                        u_lds[i] = m2; rowm[i] = j1;
                        if (i0) rowm[i0] = 0;
                    }
                    if (i0 == 0) break;
                    if (dec) { i = i0; continue; }     // strict: chase now
                    if (lane == 0) q[ne] = i0;          // tie: defer
                    ++ne;
                    break;
                }
            }
            s = e; e = ne;
        }
    }
    __syncthreads();

    // ---- exact SSP for remaining free rows (integer, deferred duals) ----
    int minv[NSLOT], way[NSLOT];
    unsigned used = 0u;

    auto expand = [&](int rr, int jpred, int Dh) {
        int d[NSLOT]; loadrow(rr, d);
        int base = Dh - u_lds[rr];
#pragma unroll
        for (int k = 0; k < NSLOT; ++k) {
            int cur = d[k] + nv[k] + base;
            // gate by used-bit: settled slots keep way[] frozen (R7 bugfix)
            bool upd = !((used >> k) & 1u) && (unsigned)cur < (unsigned)minv[k];
            minv[k] = upd ? cur : minv[k];
            way[k] = upd ? jpred : way[k];
        }
    };

    for (int i = 1; i <= N; ++i) {
        if (__builtin_amdgcn_readfirstlane(rowm[i]) != 0) continue;

        used = 0u;
        int DT = 0, freecol = 0;
#pragma unroll
        for (int k = 0; k < NSLOT; ++k) { minv[k] = INFI; way[k] = 0; }
        expand(i, 0, 0);

        int guard = 0;
        for (;;) {
            if (++guard > N + 4) break;
            // pair-tree argmin over (minv, jpk)
            int tv[8], tj[8];
#pragma unroll
            for (int t = 0; t < 8; ++t) {
                bool c = (unsigned)minv[2 * t + 1] < (unsigned)minv[2 * t];
                tv[t] = c ? minv[2 * t + 1] : minv[2 * t];
                tj[t] = c ? jpk[2 * t + 1] : jpk[2 * t];
            }
#pragma unroll
            for (int t = 0; t < 4; ++t) {
                bool c = (unsigned)tv[2 * t + 1] < (unsigned)tv[2 * t];
                tv[t] = c ? tv[2 * t + 1] : tv[2 * t];
                tj[t] = c ? tj[2 * t + 1] : tj[2 * t];
            }
            {
                bool c = (unsigned)tv[1] < (unsigned)tv[0];
                tv[0] = c ? tv[1] : tv[0]; tj[0] = c ? tj[1] : tj[0];
                c = (unsigned)tv[3] < (unsigned)tv[2];
                tv[1] = c ? tv[3] : tv[2]; tj[1] = c ? tj[3] : tj[2];
                c = (unsigned)tv[1] < (unsigned)tv[0];
                tv[0] = c ? tv[1] : tv[0]; tj[0] = c ? tj[1] : tj[0];
            }
            unsigned gmin = wave_min_u32((unsigned)tv[0]);
            if (gmin >= (unsigned)INFI) break;
            unsigned long long tm = __ballot((unsigned)tv[0] == gmin);
            DT = (int)gmin;
            freecol = 0;
            // free-column short-circuit: zero expands if any tie is free
            unsigned long long tf = tm;
            while (tf) {
                int l = __ffsll((long long)tf) - 1; tf &= tf - 1;
                int jp = __builtin_amdgcn_readlane(tj[0], l);
                if ((jp >> 11) == 0) { freecol = jp & 0x7FF; break; }
            }
            if (freecol) break;
            // settle all matched ties at gmin
            while (tm) {
                int l = __ffsll((long long)tm) - 1; tm &= tm - 1;
                int jp = __builtin_amdgcn_readlane(tj[0], l);
                int jj = jp & 0x7FF, rr = jp >> 11;
                if (lane == 0) den[jj] = DT;
                int lo = (jj - 1) >> 4, kk = (jj - 1) & 15;
                if (lane == lo) {
#pragma unroll
                    for (int k = 0; k < NSLOT; ++k)
                        if (k == kk) { minv[k] = INFI; used |= (1u << k); }
                }
                expand(rr, jj, DT);
            }
        }
        if (freecol == 0) continue;

        __syncthreads();
        // deferred dual updates (pre-augment jpk)
        if (lane == 0) u_lds[i] += DT;
#pragma unroll
        for (int k = 0; k < NSLOT; ++k) {
            if ((used >> k) & 1u) {
                int j = lane * NSLOT + k + 1;
                int dd = DT - den[j];
                nv[k] += dd;                 // v -= dd
                u_lds[jpk[k] >> 11] += dd;   // distinct rows: race-free
            }
        }
        __syncthreads();

        // augment along alternating path
        int j0 = freecol, ag = 0;
        while (j0 != 0) {
            if (++ag > N + 4) break;
            int cc = j0 - 1, lo = cc >> 4, kk = cc & 15;
            int wl = way[0];
#pragma unroll
            for (int k = 1; k < NSLOT; ++k) if (k == kk) wl = way[k];
            int j1 = __builtin_amdgcn_readlane(wl, lo);
            int np;
            if (j1 == 0) np = i;
            else {
                int c1 = j1 - 1, lo1 = c1 >> 4, kk1 = c1 & 15;
                int pl = jpk[0];
#pragma unroll
                for (int k = 1; k < NSLOT; ++k) if (k == kk1) pl = jpk[k];
                np = __builtin_amdgcn_readlane(pl, lo1) >> 11;
            }
            if (lane == lo) {
#pragma unroll
                for (int k = 0; k < NSLOT; ++k) if (k == kk) jpk[k] = (np << 11) | j0;
            }
            if (lane == 0) rowm[np] = j0;
            j0 = j1;
        }
        __syncthreads();
    }

    // ---- total matched cost: fp32 from coordinates ----
    float sum = 0.0f;
#pragma unroll
    for (int k = 0; k < NSLOT; ++k) {
        int c = lane * NSLOT + k;
        int r = jpk[k] >> 11; if (r < 1) r = 1;
        float4 qq = s1c[r];
        float sx = s2g[3 * c], sy = s2g[3 * c + 1], sz = s2g[3 * c + 2];
        float dx = qq.x - sx, dy = qq.y - sy, dz = qq.z - sz;
        sum += sqrtf(dx * dx + dy * dy + dz * dz);
    }
#pragma unroll
    for (int off = 32; off >= 1; off >>= 1) sum += __shfl_xor(sum, off);
    if (lane == 0) atomicAdd(out, sum * (1.0f / ((float)N * (float)BATCH)));
}

extern "C" void kernel_launch(void* const* d_in, const int* in_sizes, int n_in,
                              void* d_out, int out_size, void* d_ws, size_t ws_size,
                              hipStream_t stream) {
    const float* S1 = (const float*)d_in[0];
    const float* S2 = (const float*)d_in[1];
    float* out = (float*)d_out;

    size_t needD = (size_t)BATCH * N * N * sizeof(unsigned short);
    size_t needT = needD + (size_t)BATCH * N * 2 * sizeof(int);

    emd_zero_kernel<<<1, 1, 0, stream>>>(out);

    if (ws_size >= needT) {
        unsigned short* D = (unsigned short*)d_ws;
        int* V = (int*)((char*)d_ws + needD);
        int* I = V + BATCH * N;
        emd_dist_kernel<<<BATCH * N, 256, 0, stream>>>(S1, S2, D);
        emd_colmin_kernel<<<BATCH * 4, 256, 0, stream>>>(D, V, I);
        emd_jv_kernel<true><<<BATCH, 64, 0, stream>>>(S1, S2, D, V, I, out);
    } else {
        emd_jv_kernel<false><<<BATCH, 64, 0, stream>>>(S1, S2, nullptr, nullptr, nullptr, out);
    }
}